// Round 1
// baseline (1323.298 us; speedup 1.0000x reference)
//
#include <hip/hip_runtime.h>
#include <hip/hip_bf16.h>

typedef __attribute__((ext_vector_type(8))) short bf16x8;
typedef __attribute__((ext_vector_type(4))) float f32x4;

__device__ __forceinline__ unsigned short f2bf(float f) {
    unsigned int x = __float_as_uint(f);
    x += 0x7fffu + ((x >> 16) & 1u);
    return (unsigned short)(x >> 16);
}

__device__ __forceinline__ float sigmoidf_(float x) {
    return 1.f / (1.f + __expf(-x));
}
__device__ __forceinline__ float tanhf_(float x) {
    float e = __expf(-2.f * fabsf(x));
    float t = (1.f - e) / (1.f + e);
    return copysignf(t, x);
}

// ---------------------------------------------------------------------------
// Kernel A: segment-reduce hidden by mask into 50 bins, /50, concat lstm_input,
// emit bf16 padded to K=832. Grid: (64 batches, 4 chunks). Block 256.
// chunks 0..2: features [chunk*256, +256). chunk 3: features 768..831
// ---------------------------------------------------------------------------
__global__ __launch_bounds__(256) void seg_concat(
    const float* __restrict__ hidden, const int* __restrict__ mask,
    const float* __restrict__ lstm_in, short* __restrict__ concatB) {
    int b = blockIdx.x;
    int chunk = blockIdx.y;
    if (chunk == 3) {
        for (int idx = threadIdx.x; idx < 50 * 64; idx += 256) {
            int m = idx >> 6, q = idx & 63;
            float v = (q < 8) ? lstm_in[(b * 50 + m) * 8 + q] : 0.f;
            concatB[(size_t)(b * 50 + m) * 832 + 768 + q] = (short)f2bf(v);
        }
        return;
    }
    __shared__ float acc[50 * 256];
    for (int i = threadIdx.x; i < 50 * 256; i += 256) acc[i] = 0.f;
    __syncthreads();
    int lane = threadIdx.x & 63;
    int tsub = threadIdx.x >> 6;
    int c0 = chunk * 256;
    const float* hb = hidden + (size_t)b * 512 * 768;
    const int* mb = mask + b * 512;
    for (int t0 = 0; t0 < 512; t0 += 4) {
        int t = t0 + tsub;
        int d = mb[t];
        float4 v = *(const float4*)(hb + (size_t)t * 768 + c0 + lane * 4);
        if (d >= 0 && d < 50) {
            float* a = &acc[d * 256 + lane * 4];
            atomicAdd(a + 0, v.x);
            atomicAdd(a + 1, v.y);
            atomicAdd(a + 2, v.z);
            atomicAdd(a + 3, v.w);
        }
    }
    __syncthreads();
    const float inv = 1.f / 50.f;
    for (int i = threadIdx.x; i < 50 * 256; i += 256) {
        int m = i >> 8, j = i & 255;
        concatB[(size_t)(b * 50 + m) * 832 + c0 + j] = (short)f2bf(acc[i] * inv);
    }
}

// ---------------------------------------------------------------------------
// Kernel W: transpose+convert kernel weights: src[K][Nhalf] f32 (two halves)
// -> dst[N=2*Nhalf][Kpad] bf16, zero-padded for k >= Ksrc.
// Grid: (Kpad/64, N/64). Block 256.
// ---------------------------------------------------------------------------
__global__ __launch_bounds__(256) void convT(
    const float* __restrict__ srcF, const float* __restrict__ srcB,
    short* __restrict__ dst, int Ksrc, int Kpad, int Nhalf) {
    int k0 = blockIdx.x * 64, n0 = blockIdx.y * 64;
    const float* src = (n0 < Nhalf) ? srcF : srcB;
    int ncol0 = (n0 < Nhalf) ? n0 : n0 - Nhalf;
    __shared__ float tile[64][65];
    int c = threadIdx.x & 63;
    int r4 = threadIdx.x >> 6;
    for (int rr = r4; rr < 64; rr += 4) {
        int k = k0 + rr;
        tile[rr][c] = (k < Ksrc) ? src[(size_t)k * Nhalf + ncol0 + c] : 0.f;
    }
    __syncthreads();
    int rn = threadIdx.x >> 2, q = threadIdx.x & 3;
    short* d = dst + (size_t)(n0 + rn) * Kpad + k0 + q * 16;
    #pragma unroll
    for (int i = 0; i < 16; i++) d[i] = (short)f2bf(tile[q * 16 + i][rn]);
}

// ---------------------------------------------------------------------------
// bf16 MFMA GEMM: C[M][N] = A[M][Kpad] * BT[N][Kpad]^T + bias.
// 128x128 tile, BK=32, 4 waves each owning a 64x64 quadrant.
// ---------------------------------------------------------------------------
__global__ __launch_bounds__(256) void gemm_bf16(
    const short* __restrict__ A, const short* __restrict__ BT,
    const float* __restrict__ biasF, const float* __restrict__ biasB, int Nhalf,
    float* __restrict__ C, int M, int N, int Kpad) {
    __shared__ short Al[128][48];
    __shared__ short Bl[128][48];
    int m0 = blockIdx.x * 128, n0 = blockIdx.y * 128;
    int tid = threadIdx.x;
    int lane = tid & 63, w = tid >> 6;
    int arow = tid >> 1, ahalf = tid & 1;
    int wr = (w >> 1) * 64, wc = (w & 1) * 64;
    int fr = lane & 15, fq = lane >> 4;

    f32x4 acc[4][4] = {};

    for (int k0 = 0; k0 < Kpad; k0 += 32) {
        bf16x8 av = *(const bf16x8*)(A + (size_t)(m0 + arow) * Kpad + k0 + ahalf * 16);
        bf16x8 bv = *(const bf16x8*)(BT + (size_t)(n0 + arow) * Kpad + k0 + ahalf * 16);
        *(bf16x8*)&Al[arow][ahalf * 16] = av;
        *(bf16x8*)&Bl[arow][ahalf * 16] = bv;
        __syncthreads();
        bf16x8 af[4], bfv[4];
        #pragma unroll
        for (int mi = 0; mi < 4; mi++)
            af[mi] = *(const bf16x8*)&Al[wr + mi * 16 + fr][fq * 8];
        #pragma unroll
        for (int ni = 0; ni < 4; ni++)
            bfv[ni] = *(const bf16x8*)&Bl[wc + ni * 16 + fr][fq * 8];
        #pragma unroll
        for (int mi = 0; mi < 4; mi++)
            #pragma unroll
            for (int ni = 0; ni < 4; ni++)
                acc[mi][ni] = __builtin_amdgcn_mfma_f32_16x16x32_bf16(
                    af[mi], bfv[ni], acc[mi][ni], 0, 0, 0);
        __syncthreads();
    }
    #pragma unroll
    for (int mi = 0; mi < 4; mi++)
        #pragma unroll
        for (int ni = 0; ni < 4; ni++) {
            #pragma unroll
            for (int r = 0; r < 4; r++) {
                int row = m0 + wr + mi * 16 + fq * 4 + r;
                int col = n0 + wc + ni * 16 + fr;
                float bias = (col < Nhalf) ? biasF[col] : biasB[col - Nhalf];
                C[(size_t)row * N + col] = acc[mi][ni][r] + bias;
            }
        }
}

// ---------------------------------------------------------------------------
// LSTM layer-1 recurrence. One block per (batch, dir); 1024 threads.
// Wr [256][1024] f32 in registers (16x16 tile/thread). U=256.
// xz [3200][2048] f32 (fwd cols 0..1023 | bwd 1024..2047).
// out1 bf16 [3200][512] (fwd 0..255 | bwd 256..511), bwd time-reversed back.
// ---------------------------------------------------------------------------
__global__ __launch_bounds__(1024) void lstm_rec1(
    const float* __restrict__ xz, const float* __restrict__ WrF,
    const float* __restrict__ WrB, short* __restrict__ out1) {
    int b = blockIdx.x >> 1;
    int dir = blockIdx.x & 1;
    const float* Wr = dir ? WrB : WrF;
    int tid = threadIdx.x;
    int ri = tid >> 6, ci = tid & 63;

    float w[16][16];
    #pragma unroll
    for (int r = 0; r < 16; r++) {
        const float4* p = (const float4*)(Wr + (size_t)(ri * 16 + r) * 1024 + ci * 16);
        #pragma unroll
        for (int q = 0; q < 4; q++) {
            float4 v = p[q];
            w[r][q * 4 + 0] = v.x; w[r][q * 4 + 1] = v.y;
            w[r][q * 4 + 2] = v.z; w[r][q * 4 + 3] = v.w;
        }
    }

    __shared__ float h_lds[256];
    __shared__ float part[16][1024];
    __shared__ float zbuf[1024];
    float cstate = 0.f;
    if (tid < 256) h_lds[tid] = 0.f;
    __syncthreads();

    for (int s = 0; s < 50; s++) {
        int t = dir ? (49 - s) : s;
        float xzv = xz[(size_t)(b * 50 + t) * 2048 + dir * 1024 + tid];
        float accv[16];
        #pragma unroll
        for (int c = 0; c < 16; c++) accv[c] = 0.f;
        #pragma unroll
        for (int r = 0; r < 16; r++) {
            float hv = h_lds[ri * 16 + r];
            #pragma unroll
            for (int c = 0; c < 16; c++) accv[c] = fmaf(w[r][c], hv, accv[c]);
        }
        #pragma unroll
        for (int q = 0; q < 4; q++) {
            f32x4 v = {accv[q * 4], accv[q * 4 + 1], accv[q * 4 + 2], accv[q * 4 + 3]};
            *(f32x4*)&part[ri][ci * 16 + q * 4] = v;
        }
        __syncthreads();
        float zsum = xzv;
        #pragma unroll
        for (int r = 0; r < 16; r++) zsum += part[r][tid];
        zbuf[tid] = zsum;
        __syncthreads();
        if (tid < 256) {
            float iv = sigmoidf_(zbuf[tid]);
            float fv = sigmoidf_(zbuf[tid + 256]);
            float gv = tanhf_(zbuf[tid + 512]);
            float ov = sigmoidf_(zbuf[tid + 768]);
            cstate = fv * cstate + iv * gv;
            float h = ov * tanhf_(cstate);
            h_lds[tid] = h;
            out1[(size_t)(b * 50 + t) * 512 + dir * 256 + tid] = (short)f2bf(h);
        }
        __syncthreads();
    }
}

// ---------------------------------------------------------------------------
// LSTM layer-2 recurrence. One block per (batch, dir); 256 threads.
// Wr [128][512] f32 in registers (16x16 tile/thread). U=128.
// xz2 [3200][1024] (fwd 0..511 | bwd 512..1023). Only final h emitted:
// out2 [64][256] f32 (fwd 0..127 | bwd 128..255).
// ---------------------------------------------------------------------------
__global__ __launch_bounds__(256) void lstm_rec2(
    const float* __restrict__ xz, const float* __restrict__ WrF,
    const float* __restrict__ WrB, float* __restrict__ out2) {
    int b = blockIdx.x >> 1;
    int dir = blockIdx.x & 1;
    const float* Wr = dir ? WrB : WrF;
    int tid = threadIdx.x;
    int ri = tid >> 5, ci = tid & 31;

    float w[16][16];
    #pragma unroll
    for (int r = 0; r < 16; r++) {
        const float4* p = (const float4*)(Wr + (size_t)(ri * 16 + r) * 512 + ci * 16);
        #pragma unroll
        for (int q = 0; q < 4; q++) {
            float4 v = p[q];
            w[r][q * 4 + 0] = v.x; w[r][q * 4 + 1] = v.y;
            w[r][q * 4 + 2] = v.z; w[r][q * 4 + 3] = v.w;
        }
    }

    __shared__ float h_lds[128];
    __shared__ float part[8][512];
    __shared__ float zbuf[512];
    float cstate = 0.f;
    if (tid < 128) h_lds[tid] = 0.f;
    __syncthreads();

    for (int s = 0; s < 50; s++) {
        int t = dir ? (49 - s) : s;
        const float* xrow = xz + (size_t)(b * 50 + t) * 1024 + dir * 512;
        float xz0 = xrow[tid];
        float xz1 = xrow[tid + 256];
        float accv[16];
        #pragma unroll
        for (int c = 0; c < 16; c++) accv[c] = 0.f;
        #pragma unroll
        for (int r = 0; r < 16; r++) {
            float hv = h_lds[ri * 16 + r];
            #pragma unroll
            for (int c = 0; c < 16; c++) accv[c] = fmaf(w[r][c], hv, accv[c]);
        }
        #pragma unroll
        for (int q = 0; q < 4; q++) {
            f32x4 v = {accv[q * 4], accv[q * 4 + 1], accv[q * 4 + 2], accv[q * 4 + 3]};
            *(f32x4*)&part[ri][ci * 16 + q * 4] = v;
        }
        __syncthreads();
        float zs0 = xz0, zs1 = xz1;
        #pragma unroll
        for (int r = 0; r < 8; r++) {
            zs0 += part[r][tid];
            zs1 += part[r][tid + 256];
        }
        zbuf[tid] = zs0;
        zbuf[tid + 256] = zs1;
        __syncthreads();
        if (tid < 128) {
            float iv = sigmoidf_(zbuf[tid]);
            float fv = sigmoidf_(zbuf[tid + 128]);
            float gv = tanhf_(zbuf[tid + 256]);
            float ov = sigmoidf_(zbuf[tid + 384]);
            cstate = fv * cstate + iv * gv;
            float h = ov * tanhf_(cstate);
            h_lds[tid] = h;
            if (s == 49) out2[b * 256 + dir * 128 + tid] = h;
        }
        __syncthreads();
    }
}

// ---------------------------------------------------------------------------
// Dense head: 256->128->64->32->1 with relu/sigmoid. One block per batch.
// ---------------------------------------------------------------------------
__global__ __launch_bounds__(128) void dense_head(
    const float* __restrict__ out2,
    const float* __restrict__ d1w, const float* __restrict__ d1b,
    const float* __restrict__ d3w, const float* __restrict__ d3b,
    const float* __restrict__ d5w, const float* __restrict__ d5b,
    const float* __restrict__ d7w, const float* __restrict__ d7b,
    float* __restrict__ out) {
    int b = blockIdx.x;
    int tid = threadIdx.x;
    __shared__ float x[256], y1[128], y2[64], y3[32];
    x[tid] = out2[b * 256 + tid];
    x[tid + 128] = out2[b * 256 + tid + 128];
    __syncthreads();
    {
        float a = d1b[tid];
        for (int k = 0; k < 256; k++) a = fmaf(x[k], d1w[k * 128 + tid], a);
        y1[tid] = fmaxf(a, 0.f);
    }
    __syncthreads();
    if (tid < 64) {
        float a = d3b[tid];
        for (int k = 0; k < 128; k++) a = fmaf(y1[k], d3w[k * 64 + tid], a);
        y2[tid] = fmaxf(a, 0.f);
    }
    __syncthreads();
    if (tid < 32) {
        float a = d5b[tid];
        for (int k = 0; k < 64; k++) a = fmaf(y2[k], d5w[k * 32 + tid], a);
        y3[tid] = fmaxf(a, 0.f);
    }
    __syncthreads();
    if (tid == 0) {
        float a = d7b[0];
        for (int k = 0; k < 32; k++) a = fmaf(y3[k], d7w[k], a);
        out[b] = 1.f / (1.f + __expf(-a));
    }
}

extern "C" void kernel_launch(void* const* d_in, const int* in_sizes, int n_in,
                              void* d_out, int out_size, void* d_ws, size_t ws_size,
                              hipStream_t stream) {
    const float* hidden  = (const float*)d_in[0];
    const int*   mask    = (const int*)d_in[1];
    const float* lstm_in = (const float*)d_in[2];
    const float* l1f_k = (const float*)d_in[4];
    const float* l1f_r = (const float*)d_in[5];
    const float* l1f_b = (const float*)d_in[6];
    const float* l1b_k = (const float*)d_in[7];
    const float* l1b_r = (const float*)d_in[8];
    const float* l1b_b = (const float*)d_in[9];
    const float* l2f_k = (const float*)d_in[10];
    const float* l2f_r = (const float*)d_in[11];
    const float* l2f_b = (const float*)d_in[12];
    const float* l2b_k = (const float*)d_in[13];
    const float* l2b_r = (const float*)d_in[14];
    const float* l2b_b = (const float*)d_in[15];
    const float* d1w = (const float*)d_in[16];
    const float* d1b = (const float*)d_in[17];
    const float* d3w = (const float*)d_in[18];
    const float* d3b = (const float*)d_in[19];
    const float* d5w = (const float*)d_in[20];
    const float* d5b = (const float*)d_in[21];
    const float* d7w = (const float*)d_in[22];
    const float* d7b = (const float*)d_in[23];

    char* p = (char*)d_ws;
    short* concatB = (short*)p; p += (size_t)3200 * 832 * 2;
    short* wk1T    = (short*)p; p += (size_t)2048 * 832 * 2;
    short* wk2T    = (short*)p; p += (size_t)1024 * 512 * 2;
    float* xz1     = (float*)p; p += (size_t)3200 * 2048 * 4;
    short* out1    = (short*)p; p += (size_t)3200 * 512 * 2;
    float* xz2     = (float*)p; p += (size_t)3200 * 1024 * 4;
    float* out2    = (float*)p; p += (size_t)64 * 256 * 4;

    seg_concat<<<dim3(64, 4), 256, 0, stream>>>(hidden, mask, lstm_in, concatB);
    convT<<<dim3(13, 32), 256, 0, stream>>>(l1f_k, l1b_k, wk1T, 776, 832, 1024);
    convT<<<dim3(8, 16), 256, 0, stream>>>(l2f_k, l2b_k, wk2T, 512, 512, 512);
    gemm_bf16<<<dim3(25, 16), 256, 0, stream>>>(concatB, wk1T, l1f_b, l1b_b, 1024,
                                                xz1, 3200, 2048, 832);
    lstm_rec1<<<128, 1024, 0, stream>>>(xz1, l1f_r, l1b_r, out1);
    gemm_bf16<<<dim3(25, 8), 256, 0, stream>>>(out1, wk2T, l2f_b, l2b_b, 512,
                                               xz2, 3200, 1024, 512);
    lstm_rec2<<<128, 256, 0, stream>>>(xz2, l2f_r, l2b_r, out2);
    dense_head<<<64, 128, 0, stream>>>(out2, d1w, d1b, d3w, d3b, d5w, d5b,
                                       d7w, d7b, (float*)d_out);
}

// Round 2
// 1214.177 us; speedup vs baseline: 1.0899x; 1.0899x over previous
//
#include <hip/hip_runtime.h>
#include <hip/hip_bf16.h>

typedef __attribute__((ext_vector_type(8))) short bf16x8;
typedef __attribute__((ext_vector_type(4))) float f32x4;
typedef __attribute__((ext_vector_type(4))) unsigned int u32x4;

__device__ __forceinline__ unsigned short f2bf(float f) {
    unsigned int x = __float_as_uint(f);
    x += 0x7fffu + ((x >> 16) & 1u);
    return (unsigned short)(x >> 16);
}

__device__ __forceinline__ float sigmoidf_(float x) {
    return 1.f / (1.f + __expf(-x));
}
__device__ __forceinline__ float tanhf_(float x) {
    float e = __expf(-2.f * fabsf(x));
    float t = (1.f - e) / (1.f + e);
    return copysignf(t, x);
}

// ---------------------------------------------------------------------------
// Kernel A: segment-reduce hidden by mask into 50 bins, /50, concat lstm_input,
// emit bf16 padded to K=832. Grid: (64 batches, 4 chunks). Block 256.
// ---------------------------------------------------------------------------
__global__ __launch_bounds__(256) void seg_concat(
    const float* __restrict__ hidden, const int* __restrict__ mask,
    const float* __restrict__ lstm_in, short* __restrict__ concatB) {
    int b = blockIdx.x;
    int chunk = blockIdx.y;
    if (chunk == 3) {
        for (int idx = threadIdx.x; idx < 50 * 64; idx += 256) {
            int m = idx >> 6, q = idx & 63;
            float v = (q < 8) ? lstm_in[(b * 50 + m) * 8 + q] : 0.f;
            concatB[(size_t)(b * 50 + m) * 832 + 768 + q] = (short)f2bf(v);
        }
        return;
    }
    __shared__ float acc[50 * 256];
    for (int i = threadIdx.x; i < 50 * 256; i += 256) acc[i] = 0.f;
    __syncthreads();
    int lane = threadIdx.x & 63;
    int tsub = threadIdx.x >> 6;
    int c0 = chunk * 256;
    const float* hb = hidden + (size_t)b * 512 * 768;
    const int* mb = mask + b * 512;
    for (int t0 = 0; t0 < 512; t0 += 4) {
        int t = t0 + tsub;
        int d = mb[t];
        float4 v = *(const float4*)(hb + (size_t)t * 768 + c0 + lane * 4);
        if (d >= 0 && d < 50) {
            float* a = &acc[d * 256 + lane * 4];
            atomicAdd(a + 0, v.x);
            atomicAdd(a + 1, v.y);
            atomicAdd(a + 2, v.z);
            atomicAdd(a + 3, v.w);
        }
    }
    __syncthreads();
    const float inv = 1.f / 50.f;
    for (int i = threadIdx.x; i < 50 * 256; i += 256) {
        int m = i >> 8, j = i & 255;
        concatB[(size_t)(b * 50 + m) * 832 + c0 + j] = (short)f2bf(acc[i] * inv);
    }
}

// ---------------------------------------------------------------------------
// Kernel W: transpose+convert kernel weights: src[K][Nhalf] f32 (two halves)
// -> dst[N=2*Nhalf][Kpad] bf16 for the MFMA GEMM (B^T layout).
// ---------------------------------------------------------------------------
__global__ __launch_bounds__(256) void convT(
    const float* __restrict__ srcF, const float* __restrict__ srcB,
    short* __restrict__ dst, int Ksrc, int Kpad, int Nhalf) {
    int k0 = blockIdx.x * 64, n0 = blockIdx.y * 64;
    const float* src = (n0 < Nhalf) ? srcF : srcB;
    int ncol0 = (n0 < Nhalf) ? n0 : n0 - Nhalf;
    __shared__ float tile[64][65];
    int c = threadIdx.x & 63;
    int r4 = threadIdx.x >> 6;
    for (int rr = r4; rr < 64; rr += 4) {
        int k = k0 + rr;
        tile[rr][c] = (k < Ksrc) ? src[(size_t)k * Nhalf + ncol0 + c] : 0.f;
    }
    __syncthreads();
    int rn = threadIdx.x >> 2, q = threadIdx.x & 3;
    short* d = dst + (size_t)(n0 + rn) * Kpad + k0 + q * 16;
    #pragma unroll
    for (int i = 0; i < 16; i++) d[i] = (short)f2bf(tile[q * 16 + i][rn]);
}

// ---------------------------------------------------------------------------
// Kernel Wr: recurrence weights f32 [K][N] (per dir) -> bf16 [dir][K/8][N][8]
// (8 consecutive k-values interleaved per column for 16B/lane streaming).
// ---------------------------------------------------------------------------
__global__ __launch_bounds__(256) void conv_rec_w(
    const float* __restrict__ WrF, const float* __restrict__ WrB,
    short* __restrict__ dst, int K, int N) {
    int kq = blockIdx.x, dir = blockIdx.y;
    const float* src = dir ? WrB : WrF;
    short* d = dst + ((size_t)dir * (K / 8) + kq) * N * 8;
    for (int c = threadIdx.x; c < N; c += 256) {
        #pragma unroll
        for (int j = 0; j < 8; j++)
            d[c * 8 + j] = (short)f2bf(src[(size_t)(kq * 8 + j) * N + c]);
    }
}

// ---------------------------------------------------------------------------
// bf16 MFMA GEMM: C[M][N] = A[M][Kpad] * BT[N][Kpad]^T + bias.
// ---------------------------------------------------------------------------
__global__ __launch_bounds__(256) void gemm_bf16(
    const short* __restrict__ A, const short* __restrict__ BT,
    const float* __restrict__ biasF, const float* __restrict__ biasB, int Nhalf,
    float* __restrict__ C, int M, int N, int Kpad) {
    __shared__ short Al[128][48];
    __shared__ short Bl[128][48];
    int m0 = blockIdx.x * 128, n0 = blockIdx.y * 128;
    int tid = threadIdx.x;
    int lane = tid & 63, w = tid >> 6;
    int arow = tid >> 1, ahalf = tid & 1;
    int wr = (w >> 1) * 64, wc = (w & 1) * 64;
    int fr = lane & 15, fq = lane >> 4;

    f32x4 acc[4][4] = {};

    for (int k0 = 0; k0 < Kpad; k0 += 32) {
        bf16x8 av = *(const bf16x8*)(A + (size_t)(m0 + arow) * Kpad + k0 + ahalf * 16);
        bf16x8 bv = *(const bf16x8*)(BT + (size_t)(n0 + arow) * Kpad + k0 + ahalf * 16);
        *(bf16x8*)&Al[arow][ahalf * 16] = av;
        *(bf16x8*)&Bl[arow][ahalf * 16] = bv;
        __syncthreads();
        bf16x8 af[4], bfv[4];
        #pragma unroll
        for (int mi = 0; mi < 4; mi++)
            af[mi] = *(const bf16x8*)&Al[wr + mi * 16 + fr][fq * 8];
        #pragma unroll
        for (int ni = 0; ni < 4; ni++)
            bfv[ni] = *(const bf16x8*)&Bl[wc + ni * 16 + fr][fq * 8];
        #pragma unroll
        for (int mi = 0; mi < 4; mi++)
            #pragma unroll
            for (int ni = 0; ni < 4; ni++)
                acc[mi][ni] = __builtin_amdgcn_mfma_f32_16x16x32_bf16(
                    af[mi], bfv[ni], acc[mi][ni], 0, 0, 0);
        __syncthreads();
    }
    #pragma unroll
    for (int mi = 0; mi < 4; mi++)
        #pragma unroll
        for (int ni = 0; ni < 4; ni++) {
            #pragma unroll
            for (int r = 0; r < 4; r++) {
                int row = m0 + wr + mi * 16 + fq * 4 + r;
                int col = n0 + wc + ni * 16 + fr;
                float bias = (col < Nhalf) ? biasF[col] : biasB[col - Nhalf];
                C[(size_t)row * N + col] = acc[mi][ni][r] + bias;
            }
        }
}

// ---------------------------------------------------------------------------
// LSTM layer-1 recurrence. One block per (batch, dir); 1024 threads.
// Weights bf16 [32 kq][1024 col][8]: kq<9 LDS-resident, rest streamed from L2
// each step (h-independent stream). Thread owns one z-column.
// ---------------------------------------------------------------------------
#define NKQ1 32
#define NKQ1_LDS 9

__global__ __launch_bounds__(1024) void lstm_rec1(
    const float* __restrict__ xz, const short* __restrict__ w1T8,
    short* __restrict__ out1) {
    int b = blockIdx.x >> 1, dir = blockIdx.x & 1;
    const short* wbase = w1T8 + (size_t)dir * NKQ1 * 1024 * 8;
    extern __shared__ char smem[];
    short* wlds = (short*)smem;                              // 9*1024*8 bf16
    float* h_lds = (float*)(smem + NKQ1_LDS * 1024 * 8 * 2); // 256 f32
    float* zbuf = h_lds + 256;                               // 1024 f32
    int tid = threadIdx.x;

    #pragma unroll
    for (int kq = 0; kq < NKQ1_LDS; kq++)
        *(bf16x8*)&wlds[(kq * 1024 + tid) * 8] =
            *(const bf16x8*)&wbase[((size_t)kq * 1024 + tid) * 8];

    float cstate = 0.f;
    if (tid < 256) h_lds[tid] = 0.f;
    __syncthreads();

    for (int s = 0; s < 50; s++) {
        int t = dir ? 49 - s : s;
        float a0 = xz[(size_t)(b * 50 + t) * 2048 + dir * 1024 + tid];
        float a1 = 0.f, a2 = 0.f, a3 = 0.f;
        #pragma unroll
        for (int kq = 0; kq < NKQ1; kq++) {
            u32x4 wu;
            if (kq < NKQ1_LDS)
                wu = *(const u32x4*)&wlds[(kq * 1024 + tid) * 8];
            else
                wu = *(const u32x4*)&wbase[((size_t)kq * 1024 + tid) * 8];
            f32x4 ha = *(const f32x4*)&h_lds[kq * 8];
            f32x4 hb = *(const f32x4*)&h_lds[kq * 8 + 4];
            a0 = fmaf(__uint_as_float(wu.x << 16), ha.x, a0);
            a1 = fmaf(__uint_as_float(wu.x & 0xffff0000u), ha.y, a1);
            a2 = fmaf(__uint_as_float(wu.y << 16), ha.z, a2);
            a3 = fmaf(__uint_as_float(wu.y & 0xffff0000u), ha.w, a3);
            a0 = fmaf(__uint_as_float(wu.z << 16), hb.x, a0);
            a1 = fmaf(__uint_as_float(wu.z & 0xffff0000u), hb.y, a1);
            a2 = fmaf(__uint_as_float(wu.w << 16), hb.z, a2);
            a3 = fmaf(__uint_as_float(wu.w & 0xffff0000u), hb.w, a3);
        }
        zbuf[tid] = (a0 + a1) + (a2 + a3);
        __syncthreads();
        if (tid < 256) {
            float iv = sigmoidf_(zbuf[tid]);
            float fv = sigmoidf_(zbuf[tid + 256]);
            float gv = tanhf_(zbuf[tid + 512]);
            float ov = sigmoidf_(zbuf[tid + 768]);
            cstate = fv * cstate + iv * gv;
            float h = ov * tanhf_(cstate);
            h_lds[tid] = h;
            out1[(size_t)(b * 50 + t) * 512 + dir * 256 + tid] = (short)f2bf(h);
        }
        __syncthreads();
    }
}

// ---------------------------------------------------------------------------
// LSTM layer-2 recurrence. One block per (batch, dir); 512 threads.
// Weights bf16 [16 kq][512 col][8] FULLY LDS-resident (128 KB).
// ---------------------------------------------------------------------------
#define NKQ2 16

__global__ __launch_bounds__(512) void lstm_rec2(
    const float* __restrict__ xz, const short* __restrict__ w2T8,
    float* __restrict__ out2) {
    int b = blockIdx.x >> 1, dir = blockIdx.x & 1;
    const short* wbase = w2T8 + (size_t)dir * NKQ2 * 512 * 8;
    extern __shared__ char smem[];
    short* wlds = (short*)smem;                          // 16*512*8 bf16
    float* h_lds = (float*)(smem + NKQ2 * 512 * 8 * 2);  // 128 f32
    float* zbuf = h_lds + 128;                           // 512 f32
    int tid = threadIdx.x;

    #pragma unroll
    for (int kq = 0; kq < NKQ2; kq++)
        *(bf16x8*)&wlds[(kq * 512 + tid) * 8] =
            *(const bf16x8*)&wbase[((size_t)kq * 512 + tid) * 8];

    float cstate = 0.f;
    if (tid < 128) h_lds[tid] = 0.f;
    __syncthreads();

    for (int s = 0; s < 50; s++) {
        int t = dir ? 49 - s : s;
        float a0 = xz[(size_t)(b * 50 + t) * 1024 + dir * 512 + tid];
        float a1 = 0.f, a2 = 0.f, a3 = 0.f;
        #pragma unroll
        for (int kq = 0; kq < NKQ2; kq++) {
            u32x4 wu = *(const u32x4*)&wlds[(kq * 512 + tid) * 8];
            f32x4 ha = *(const f32x4*)&h_lds[kq * 8];
            f32x4 hb = *(const f32x4*)&h_lds[kq * 8 + 4];
            a0 = fmaf(__uint_as_float(wu.x << 16), ha.x, a0);
            a1 = fmaf(__uint_as_float(wu.x & 0xffff0000u), ha.y, a1);
            a2 = fmaf(__uint_as_float(wu.y << 16), ha.z, a2);
            a3 = fmaf(__uint_as_float(wu.y & 0xffff0000u), ha.w, a3);
            a0 = fmaf(__uint_as_float(wu.z << 16), hb.x, a0);
            a1 = fmaf(__uint_as_float(wu.z & 0xffff0000u), hb.y, a1);
            a2 = fmaf(__uint_as_float(wu.w << 16), hb.z, a2);
            a3 = fmaf(__uint_as_float(wu.w & 0xffff0000u), hb.w, a3);
        }
        zbuf[tid] = (a0 + a1) + (a2 + a3);
        __syncthreads();
        if (tid < 128) {
            float iv = sigmoidf_(zbuf[tid]);
            float fv = sigmoidf_(zbuf[tid + 128]);
            float gv = tanhf_(zbuf[tid + 256]);
            float ov = sigmoidf_(zbuf[tid + 384]);
            cstate = fv * cstate + iv * gv;
            float h = ov * tanhf_(cstate);
            h_lds[tid] = h;
            if (s == 49) out2[b * 256 + dir * 128 + tid] = h;
        }
        __syncthreads();
    }
}

// ---------------------------------------------------------------------------
// Dense head: 256->128->64->32->1 with relu/sigmoid. One block per batch.
// ---------------------------------------------------------------------------
__global__ __launch_bounds__(128) void dense_head(
    const float* __restrict__ out2,
    const float* __restrict__ d1w, const float* __restrict__ d1b,
    const float* __restrict__ d3w, const float* __restrict__ d3b,
    const float* __restrict__ d5w, const float* __restrict__ d5b,
    const float* __restrict__ d7w, const float* __restrict__ d7b,
    float* __restrict__ out) {
    int b = blockIdx.x;
    int tid = threadIdx.x;
    __shared__ float x[256], y1[128], y2[64], y3[32];
    x[tid] = out2[b * 256 + tid];
    x[tid + 128] = out2[b * 256 + tid + 128];
    __syncthreads();
    {
        float a = d1b[tid];
        for (int k = 0; k < 256; k++) a = fmaf(x[k], d1w[k * 128 + tid], a);
        y1[tid] = fmaxf(a, 0.f);
    }
    __syncthreads();
    if (tid < 64) {
        float a = d3b[tid];
        for (int k = 0; k < 128; k++) a = fmaf(y1[k], d3w[k * 64 + tid], a);
        y2[tid] = fmaxf(a, 0.f);
    }
    __syncthreads();
    if (tid < 32) {
        float a = d5b[tid];
        for (int k = 0; k < 64; k++) a = fmaf(y2[k], d5w[k * 32 + tid], a);
        y3[tid] = fmaxf(a, 0.f);
    }
    __syncthreads();
    if (tid == 0) {
        float a = d7b[0];
        for (int k = 0; k < 32; k++) a = fmaf(y3[k], d7w[k], a);
        out[b] = 1.f / (1.f + __expf(-a));
    }
}

extern "C" void kernel_launch(void* const* d_in, const int* in_sizes, int n_in,
                              void* d_out, int out_size, void* d_ws, size_t ws_size,
                              hipStream_t stream) {
    const float* hidden  = (const float*)d_in[0];
    const int*   mask    = (const int*)d_in[1];
    const float* lstm_in = (const float*)d_in[2];
    const float* l1f_k = (const float*)d_in[4];
    const float* l1f_r = (const float*)d_in[5];
    const float* l1f_b = (const float*)d_in[6];
    const float* l1b_k = (const float*)d_in[7];
    const float* l1b_r = (const float*)d_in[8];
    const float* l1b_b = (const float*)d_in[9];
    const float* l2f_k = (const float*)d_in[10];
    const float* l2f_r = (const float*)d_in[11];
    const float* l2f_b = (const float*)d_in[12];
    const float* l2b_k = (const float*)d_in[13];
    const float* l2b_r = (const float*)d_in[14];
    const float* l2b_b = (const float*)d_in[15];
    const float* d1w = (const float*)d_in[16];
    const float* d1b = (const float*)d_in[17];
    const float* d3w = (const float*)d_in[18];
    const float* d3b = (const float*)d_in[19];
    const float* d5w = (const float*)d_in[20];
    const float* d5b = (const float*)d_in[21];
    const float* d7w = (const float*)d_in[22];
    const float* d7b = (const float*)d_in[23];

    char* p = (char*)d_ws;
    short* concatB = (short*)p; p += (size_t)3200 * 832 * 2;
    short* wk1T    = (short*)p; p += (size_t)2048 * 832 * 2;
    short* wk2T    = (short*)p; p += (size_t)1024 * 512 * 2;
    float* xz1     = (float*)p; p += (size_t)3200 * 2048 * 4;
    short* out1    = (short*)p; p += (size_t)3200 * 512 * 2;
    float* xz2     = (float*)p; p += (size_t)3200 * 1024 * 4;
    float* out2    = (float*)p; p += (size_t)64 * 256 * 4;
    short* w1T8    = (short*)p; p += (size_t)2 * 32 * 1024 * 8 * 2;
    short* w2T8    = (short*)p; p += (size_t)2 * 16 * 512 * 8 * 2;

    const int lds1 = NKQ1_LDS * 1024 * 8 * 2 + 256 * 4 + 1024 * 4;  // 152576
    const int lds2 = NKQ2 * 512 * 8 * 2 + 128 * 4 + 512 * 4;        // 133632
    hipFuncSetAttribute((const void*)lstm_rec1,
                        hipFuncAttributeMaxDynamicSharedMemorySize, lds1);
    hipFuncSetAttribute((const void*)lstm_rec2,
                        hipFuncAttributeMaxDynamicSharedMemorySize, lds2);

    seg_concat<<<dim3(64, 4), 256, 0, stream>>>(hidden, mask, lstm_in, concatB);
    convT<<<dim3(13, 32), 256, 0, stream>>>(l1f_k, l1b_k, wk1T, 776, 832, 1024);
    convT<<<dim3(8, 16), 256, 0, stream>>>(l2f_k, l2b_k, wk2T, 512, 512, 512);
    conv_rec_w<<<dim3(32, 2), 256, 0, stream>>>(l1f_r, l1b_r, w1T8, 256, 1024);
    conv_rec_w<<<dim3(16, 2), 256, 0, stream>>>(l2f_r, l2b_r, w2T8, 128, 512);
    gemm_bf16<<<dim3(25, 16), 256, 0, stream>>>(concatB, wk1T, l1f_b, l1b_b, 1024,
                                                xz1, 3200, 2048, 832);
    lstm_rec1<<<128, 1024, lds1, stream>>>(xz1, w1T8, out1);
    gemm_bf16<<<dim3(25, 8), 256, 0, stream>>>(out1, wk2T, l2f_b, l2b_b, 512,
                                               xz2, 3200, 1024, 512);
    lstm_rec2<<<128, 512, lds2, stream>>>(xz2, w2T8, out2);
    dense_head<<<64, 128, 0, stream>>>(out2, d1w, d1b, d3w, d3b, d5w, d5b,
                                       d7w, d7b, (float*)d_out);
}

// Round 3
// 403.678 us; speedup vs baseline: 3.2781x; 3.0078x over previous
//
#include <hip/hip_runtime.h>
#include <hip/hip_bf16.h>

typedef __attribute__((ext_vector_type(8))) short bf16x8;
typedef __attribute__((ext_vector_type(4))) float f32x4;
typedef __attribute__((ext_vector_type(4))) unsigned int u32x4;
typedef _Float16 half2_ __attribute__((ext_vector_type(2)));

__device__ __forceinline__ unsigned short f2bf(float f) {
    unsigned int x = __float_as_uint(f);
    x += 0x7fffu + ((x >> 16) & 1u);
    return (unsigned short)(x >> 16);
}

__device__ __forceinline__ float sigmoidf_(float x) {
    return 1.f / (1.f + __expf(-x));
}
__device__ __forceinline__ float tanhf_(float x) {
    float e = __expf(-2.f * fabsf(x));
    float t = (1.f - e) / (1.f + e);
    return copysignf(t, x);
}

__device__ __forceinline__ float fdot2_(unsigned int w, unsigned int h, float acc) {
#if __has_builtin(__builtin_amdgcn_fdot2)
    return __builtin_amdgcn_fdot2(__builtin_bit_cast(half2_, w),
                                  __builtin_bit_cast(half2_, h), acc, false);
#else
    half2_ a = __builtin_bit_cast(half2_, w);
    half2_ b = __builtin_bit_cast(half2_, h);
    return acc + (float)a.x * (float)b.x + (float)a.y * (float)b.y;
#endif
}

// ---------------------------------------------------------------------------
// Kernel A: segment-reduce hidden by mask into 50 bins, /50, concat lstm_input,
// emit bf16 padded to K=832. Grid: (64 batches, 4 chunks). Block 256.
// ---------------------------------------------------------------------------
__global__ __launch_bounds__(256) void seg_concat(
    const float* __restrict__ hidden, const int* __restrict__ mask,
    const float* __restrict__ lstm_in, short* __restrict__ concatB) {
    int b = blockIdx.x;
    int chunk = blockIdx.y;
    if (chunk == 3) {
        for (int idx = threadIdx.x; idx < 50 * 64; idx += 256) {
            int m = idx >> 6, q = idx & 63;
            float v = (q < 8) ? lstm_in[(b * 50 + m) * 8 + q] : 0.f;
            concatB[(size_t)(b * 50 + m) * 832 + 768 + q] = (short)f2bf(v);
        }
        return;
    }
    __shared__ float acc[50 * 256];
    for (int i = threadIdx.x; i < 50 * 256; i += 256) acc[i] = 0.f;
    __syncthreads();
    int lane = threadIdx.x & 63;
    int tsub = threadIdx.x >> 6;
    int c0 = chunk * 256;
    const float* hb = hidden + (size_t)b * 512 * 768;
    const int* mb = mask + b * 512;
    for (int t0 = 0; t0 < 512; t0 += 4) {
        int t = t0 + tsub;
        int d = mb[t];
        float4 v = *(const float4*)(hb + (size_t)t * 768 + c0 + lane * 4);
        if (d >= 0 && d < 50) {
            float* a = &acc[d * 256 + lane * 4];
            atomicAdd(a + 0, v.x);
            atomicAdd(a + 1, v.y);
            atomicAdd(a + 2, v.z);
            atomicAdd(a + 3, v.w);
        }
    }
    __syncthreads();
    const float inv = 1.f / 50.f;
    for (int i = threadIdx.x; i < 50 * 256; i += 256) {
        int m = i >> 8, j = i & 255;
        concatB[(size_t)(b * 50 + m) * 832 + c0 + j] = (short)f2bf(acc[i] * inv);
    }
}

// ---------------------------------------------------------------------------
// Kernel W: transpose+convert kernel weights: src[K][Nhalf] f32 (two halves)
// -> dst[N=2*Nhalf][Kpad] bf16 for the MFMA GEMM (B^T layout).
// ---------------------------------------------------------------------------
__global__ __launch_bounds__(256) void convT(
    const float* __restrict__ srcF, const float* __restrict__ srcB,
    short* __restrict__ dst, int Ksrc, int Kpad, int Nhalf) {
    int k0 = blockIdx.x * 64, n0 = blockIdx.y * 64;
    const float* src = (n0 < Nhalf) ? srcF : srcB;
    int ncol0 = (n0 < Nhalf) ? n0 : n0 - Nhalf;
    __shared__ float tile[64][65];
    int c = threadIdx.x & 63;
    int r4 = threadIdx.x >> 6;
    for (int rr = r4; rr < 64; rr += 4) {
        int k = k0 + rr;
        tile[rr][c] = (k < Ksrc) ? src[(size_t)k * Nhalf + ncol0 + c] : 0.f;
    }
    __syncthreads();
    int rn = threadIdx.x >> 2, q = threadIdx.x & 3;
    short* d = dst + (size_t)(n0 + rn) * Kpad + k0 + q * 16;
    #pragma unroll
    for (int i = 0; i < 16; i++) d[i] = (short)f2bf(tile[q * 16 + i][rn]);
}

// ---------------------------------------------------------------------------
// Kernel Wr: recurrence weights f32 [K][N] (per dir) -> u32 [2][K/8][N][4]
// packed f16 pairs: dst[dir][kq>>2][c][kq&3] = (f16(W[2kq][c]), f16(W[2kq+1][c]))
// Grid: (K/2, 2). Block 256.
// ---------------------------------------------------------------------------
__global__ __launch_bounds__(256) void conv_rec_pack(
    const float* __restrict__ WrF, const float* __restrict__ WrB,
    unsigned int* __restrict__ dst, int K, int N) {
    int kq = blockIdx.x, dir = blockIdx.y;
    const float* src = dir ? WrB : WrF;
    int kqq = kq >> 2, q = kq & 3;
    for (int c = threadIdx.x; c < N; c += 256) {
        half2_ h;
        h.x = (_Float16)src[(size_t)(2 * kq) * N + c];
        h.y = (_Float16)src[(size_t)(2 * kq + 1) * N + c];
        dst[(((size_t)dir * (K / 8) + kqq) * N + c) * 4 + q] =
            __builtin_bit_cast(unsigned int, h);
    }
}

// ---------------------------------------------------------------------------
// bf16 MFMA GEMM: C[M][N] = A[M][Kpad] * BT[N][Kpad]^T + bias.
// ---------------------------------------------------------------------------
__global__ __launch_bounds__(256) void gemm_bf16(
    const short* __restrict__ A, const short* __restrict__ BT,
    const float* __restrict__ biasF, const float* __restrict__ biasB, int Nhalf,
    float* __restrict__ C, int M, int N, int Kpad) {
    __shared__ short Al[128][48];
    __shared__ short Bl[128][48];
    int m0 = blockIdx.x * 128, n0 = blockIdx.y * 128;
    int tid = threadIdx.x;
    int lane = tid & 63, w = tid >> 6;
    int arow = tid >> 1, ahalf = tid & 1;
    int wr = (w >> 1) * 64, wc = (w & 1) * 64;
    int fr = lane & 15, fq = lane >> 4;

    f32x4 acc[4][4] = {};

    for (int k0 = 0; k0 < Kpad; k0 += 32) {
        bf16x8 av = *(const bf16x8*)(A + (size_t)(m0 + arow) * Kpad + k0 + ahalf * 16);
        bf16x8 bv = *(const bf16x8*)(BT + (size_t)(n0 + arow) * Kpad + k0 + ahalf * 16);
        *(bf16x8*)&Al[arow][ahalf * 16] = av;
        *(bf16x8*)&Bl[arow][ahalf * 16] = bv;
        __syncthreads();
        bf16x8 af[4], bfv[4];
        #pragma unroll
        for (int mi = 0; mi < 4; mi++)
            af[mi] = *(const bf16x8*)&Al[wr + mi * 16 + fr][fq * 8];
        #pragma unroll
        for (int ni = 0; ni < 4; ni++)
            bfv[ni] = *(const bf16x8*)&Bl[wc + ni * 16 + fr][fq * 8];
        #pragma unroll
        for (int mi = 0; mi < 4; mi++)
            #pragma unroll
            for (int ni = 0; ni < 4; ni++)
                acc[mi][ni] = __builtin_amdgcn_mfma_f32_16x16x32_bf16(
                    af[mi], bfv[ni], acc[mi][ni], 0, 0, 0);
        __syncthreads();
    }
    #pragma unroll
    for (int mi = 0; mi < 4; mi++)
        #pragma unroll
        for (int ni = 0; ni < 4; ni++) {
            #pragma unroll
            for (int r = 0; r < 4; r++) {
                int row = m0 + wr + mi * 16 + fq * 4 + r;
                int col = n0 + wc + ni * 16 + fr;
                float bias = (col < Nhalf) ? biasF[col] : biasB[col - Nhalf];
                C[(size_t)row * N + col] = acc[mi][ni][r] + bias;
            }
        }
}

// ---------------------------------------------------------------------------
// LSTM layer-1 recurrence. One block per (batch, dir); 512 threads.
// Thread owns cols t and t+512. Weights f16-pair-packed: k<192 in registers
// (2 cols x 24 u32x4), k in [192,256) in LDS [8][1024][4] u32. Zero global
// weight traffic in the steady state.
// ---------------------------------------------------------------------------
#define KQQ_REG 24
#define KQQ_LDS 8

__global__ __launch_bounds__(512, 2) void lstm_rec1(
    const float* __restrict__ xz, const unsigned int* __restrict__ wp,
    short* __restrict__ out1) {
    int b = blockIdx.x >> 1, dir = blockIdx.x & 1;
    const unsigned int* wd = wp + (size_t)dir * 32 * 1024 * 4;
    extern __shared__ char smem[];
    unsigned int* Wl = (unsigned int*)smem;               // 8*1024*4 u32 = 128 KB
    unsigned int* h2u = (unsigned int*)(smem + 131072);   // 128 u32 (256 f16)
    float* zbuf = (float*)(smem + 131072 + 512);          // 1024 f32
    int t = threadIdx.x;
    int cA = t, cB = t + 512;

    u32x4 wA[KQQ_REG], wB[KQQ_REG];
    #pragma unroll
    for (int g = 0; g < KQQ_REG; g++) {
        wA[g] = *(const u32x4*)&wd[((size_t)g * 1024 + cA) * 4];
        wB[g] = *(const u32x4*)&wd[((size_t)g * 1024 + cB) * 4];
    }
    #pragma unroll
    for (int g = 0; g < KQQ_LDS; g++) {
        *(u32x4*)&Wl[(g * 1024 + cA) * 4] =
            *(const u32x4*)&wd[((size_t)(KQQ_REG + g) * 1024 + cA) * 4];
        *(u32x4*)&Wl[(g * 1024 + cB) * 4] =
            *(const u32x4*)&wd[((size_t)(KQQ_REG + g) * 1024 + cB) * 4];
    }
    if (t < 128) h2u[t] = 0u;
    float cstate = 0.f;
    __syncthreads();

    for (int s = 0; s < 50; s++) {
        int tt = dir ? 49 - s : s;
        const float* xrow = xz + (size_t)(b * 50 + tt) * 2048 + dir * 1024;
        float zA0 = xrow[cA], zA1 = 0.f;
        float zB0 = xrow[cB], zB1 = 0.f;
        #pragma unroll
        for (int g = 0; g < KQQ_REG; g++) {
            u32x4 h4 = *(const u32x4*)&h2u[g * 4];
            zA0 = fdot2_(wA[g].x, h4.x, zA0);
            zA1 = fdot2_(wA[g].y, h4.y, zA1);
            zA0 = fdot2_(wA[g].z, h4.z, zA0);
            zA1 = fdot2_(wA[g].w, h4.w, zA1);
            zB0 = fdot2_(wB[g].x, h4.x, zB0);
            zB1 = fdot2_(wB[g].y, h4.y, zB1);
            zB0 = fdot2_(wB[g].z, h4.z, zB0);
            zB1 = fdot2_(wB[g].w, h4.w, zB1);
        }
        #pragma unroll
        for (int g = 0; g < KQQ_LDS; g++) {
            u32x4 h4 = *(const u32x4*)&h2u[(KQQ_REG + g) * 4];
            u32x4 wa = *(const u32x4*)&Wl[(g * 1024 + cA) * 4];
            u32x4 wb = *(const u32x4*)&Wl[(g * 1024 + cB) * 4];
            zA0 = fdot2_(wa.x, h4.x, zA0);
            zA1 = fdot2_(wa.y, h4.y, zA1);
            zA0 = fdot2_(wa.z, h4.z, zA0);
            zA1 = fdot2_(wa.w, h4.w, zA1);
            zB0 = fdot2_(wb.x, h4.x, zB0);
            zB1 = fdot2_(wb.y, h4.y, zB1);
            zB0 = fdot2_(wb.z, h4.z, zB0);
            zB1 = fdot2_(wb.w, h4.w, zB1);
        }
        zbuf[cA] = zA0 + zA1;
        zbuf[cB] = zB0 + zB1;
        __syncthreads();
        if (t < 256) {
            float iv = sigmoidf_(zbuf[t]);
            float fv = sigmoidf_(zbuf[t + 256]);
            float gv = tanhf_(zbuf[t + 512]);
            float ov = sigmoidf_(zbuf[t + 768]);
            cstate = fv * cstate + iv * gv;
            float h = ov * tanhf_(cstate);
            ((_Float16*)h2u)[t] = (_Float16)h;
            out1[(size_t)(b * 50 + tt) * 512 + dir * 256 + t] = (short)f2bf(h);
        }
        __syncthreads();
    }
}

// ---------------------------------------------------------------------------
// LSTM layer-2 recurrence. One block per (batch, dir); 512 threads.
// Thread owns col t; ALL K=128 weights in registers (16 u32x4).
// ---------------------------------------------------------------------------
__global__ __launch_bounds__(512, 2) void lstm_rec2(
    const float* __restrict__ xz, const unsigned int* __restrict__ wp,
    float* __restrict__ out2) {
    int b = blockIdx.x >> 1, dir = blockIdx.x & 1;
    const unsigned int* wd = wp + (size_t)dir * 16 * 512 * 4;
    __shared__ unsigned int h2u[64];
    __shared__ float zbuf[512];
    int t = threadIdx.x;
    u32x4 w[16];
    #pragma unroll
    for (int g = 0; g < 16; g++)
        w[g] = *(const u32x4*)&wd[((size_t)g * 512 + t) * 4];
    if (t < 64) h2u[t] = 0u;
    float cstate = 0.f;
    __syncthreads();

    for (int s = 0; s < 50; s++) {
        int tt = dir ? 49 - s : s;
        float z0 = xz[(size_t)(b * 50 + tt) * 1024 + dir * 512 + t], z1 = 0.f;
        #pragma unroll
        for (int g = 0; g < 16; g++) {
            u32x4 h4 = *(const u32x4*)&h2u[g * 4];
            z0 = fdot2_(w[g].x, h4.x, z0);
            z1 = fdot2_(w[g].y, h4.y, z1);
            z0 = fdot2_(w[g].z, h4.z, z0);
            z1 = fdot2_(w[g].w, h4.w, z1);
        }
        zbuf[t] = z0 + z1;
        __syncthreads();
        if (t < 128) {
            float iv = sigmoidf_(zbuf[t]);
            float fv = sigmoidf_(zbuf[t + 128]);
            float gv = tanhf_(zbuf[t + 256]);
            float ov = sigmoidf_(zbuf[t + 384]);
            cstate = fv * cstate + iv * gv;
            float h = ov * tanhf_(cstate);
            ((_Float16*)h2u)[t] = (_Float16)h;
            if (s == 49) out2[b * 256 + dir * 128 + t] = h;
        }
        __syncthreads();
    }
}

// ---------------------------------------------------------------------------
// Dense head: 256->128->64->32->1 with relu/sigmoid. One block per batch.
// ---------------------------------------------------------------------------
__global__ __launch_bounds__(128) void dense_head(
    const float* __restrict__ out2,
    const float* __restrict__ d1w, const float* __restrict__ d1b,
    const float* __restrict__ d3w, const float* __restrict__ d3b,
    const float* __restrict__ d5w, const float* __restrict__ d5b,
    const float* __restrict__ d7w, const float* __restrict__ d7b,
    float* __restrict__ out) {
    int b = blockIdx.x;
    int tid = threadIdx.x;
    __shared__ float x[256], y1[128], y2[64], y3[32];
    x[tid] = out2[b * 256 + tid];
    x[tid + 128] = out2[b * 256 + tid + 128];
    __syncthreads();
    {
        float a = d1b[tid];
        for (int k = 0; k < 256; k++) a = fmaf(x[k], d1w[k * 128 + tid], a);
        y1[tid] = fmaxf(a, 0.f);
    }
    __syncthreads();
    if (tid < 64) {
        float a = d3b[tid];
        for (int k = 0; k < 128; k++) a = fmaf(y1[k], d3w[k * 64 + tid], a);
        y2[tid] = fmaxf(a, 0.f);
    }
    __syncthreads();
    if (tid < 32) {
        float a = d5b[tid];
        for (int k = 0; k < 64; k++) a = fmaf(y2[k], d5w[k * 32 + tid], a);
        y3[tid] = fmaxf(a, 0.f);
    }
    __syncthreads();
    if (tid == 0) {
        float a = d7b[0];
        for (int k = 0; k < 32; k++) a = fmaf(y3[k], d7w[k], a);
        out[b] = 1.f / (1.f + __expf(-a));
    }
}

extern "C" void kernel_launch(void* const* d_in, const int* in_sizes, int n_in,
                              void* d_out, int out_size, void* d_ws, size_t ws_size,
                              hipStream_t stream) {
    const float* hidden  = (const float*)d_in[0];
    const int*   mask    = (const int*)d_in[1];
    const float* lstm_in = (const float*)d_in[2];
    const float* l1f_k = (const float*)d_in[4];
    const float* l1f_r = (const float*)d_in[5];
    const float* l1f_b = (const float*)d_in[6];
    const float* l1b_k = (const float*)d_in[7];
    const float* l1b_r = (const float*)d_in[8];
    const float* l1b_b = (const float*)d_in[9];
    const float* l2f_k = (const float*)d_in[10];
    const float* l2f_r = (const float*)d_in[11];
    const float* l2f_b = (const float*)d_in[12];
    const float* l2b_k = (const float*)d_in[13];
    const float* l2b_r = (const float*)d_in[14];
    const float* l2b_b = (const float*)d_in[15];
    const float* d1w = (const float*)d_in[16];
    const float* d1b = (const float*)d_in[17];
    const float* d3w = (const float*)d_in[18];
    const float* d3b = (const float*)d_in[19];
    const float* d5w = (const float*)d_in[20];
    const float* d5b = (const float*)d_in[21];
    const float* d7w = (const float*)d_in[22];
    const float* d7b = (const float*)d_in[23];

    char* p = (char*)d_ws;
    short* concatB = (short*)p; p += (size_t)3200 * 832 * 2;
    short* wk1T    = (short*)p; p += (size_t)2048 * 832 * 2;
    short* wk2T    = (short*)p; p += (size_t)1024 * 512 * 2;
    float* xz1     = (float*)p; p += (size_t)3200 * 2048 * 4;
    short* out1    = (short*)p; p += (size_t)3200 * 512 * 2;
    float* xz2     = (float*)p; p += (size_t)3200 * 1024 * 4;
    float* out2    = (float*)p; p += (size_t)64 * 256 * 4;
    unsigned int* wp1 = (unsigned int*)p; p += (size_t)2 * 32 * 1024 * 4 * 4;
    unsigned int* wp2 = (unsigned int*)p; p += (size_t)2 * 16 * 512 * 4 * 4;

    const int lds1 = 131072 + 512 + 4096;  // 135680
    hipFuncSetAttribute((const void*)lstm_rec1,
                        hipFuncAttributeMaxDynamicSharedMemorySize, lds1);

    seg_concat<<<dim3(64, 4), 256, 0, stream>>>(hidden, mask, lstm_in, concatB);
    convT<<<dim3(13, 32), 256, 0, stream>>>(l1f_k, l1b_k, wk1T, 776, 832, 1024);
    convT<<<dim3(8, 16), 256, 0, stream>>>(l2f_k, l2b_k, wk2T, 512, 512, 512);
    conv_rec_pack<<<dim3(128, 2), 256, 0, stream>>>(l1f_r, l1b_r, wp1, 256, 1024);
    conv_rec_pack<<<dim3(64, 2), 256, 0, stream>>>(l2f_r, l2b_r, wp2, 128, 512);
    gemm_bf16<<<dim3(25, 16), 256, 0, stream>>>(concatB, wk1T, l1f_b, l1b_b, 1024,
                                                xz1, 3200, 2048, 832);
    lstm_rec1<<<128, 512, lds1, stream>>>(xz1, wp1, out1);
    gemm_bf16<<<dim3(25, 8), 256, 0, stream>>>(out1, wk2T, l2f_b, l2b_b, 512,
                                               xz2, 3200, 1024, 512);
    lstm_rec2<<<128, 512, 0, stream>>>(xz2, wp2, out2);
    dense_head<<<64, 128, 0, stream>>>(out2, d1w, d1b, d3w, d3b, d5w, d5b,
                                       d7w, d7b, (float*)d_out);
}

// Round 4
// 289.657 us; speedup vs baseline: 4.5685x; 1.3936x over previous
//
#include <hip/hip_runtime.h>
#include <hip/hip_bf16.h>

typedef __attribute__((ext_vector_type(8))) short bf16x8;
typedef __attribute__((ext_vector_type(4))) float f32x4;
typedef __attribute__((ext_vector_type(4))) unsigned int u32x4;
typedef _Float16 half2_ __attribute__((ext_vector_type(2)));

__device__ __forceinline__ unsigned short f2bf(float f) {
    unsigned int x = __float_as_uint(f);
    x += 0x7fffu + ((x >> 16) & 1u);
    return (unsigned short)(x >> 16);
}

__device__ __forceinline__ float sigmoidf_(float x) {
    return 1.f / (1.f + __expf(-x));
}
__device__ __forceinline__ float tanhf_(float x) {
    float e = __expf(-2.f * fabsf(x));
    float t = (1.f - e) / (1.f + e);
    return copysignf(t, x);
}

__device__ __forceinline__ float fdot2_(unsigned int w, unsigned int h, float acc) {
#if __has_builtin(__builtin_amdgcn_fdot2)
    return __builtin_amdgcn_fdot2(__builtin_bit_cast(half2_, w),
                                  __builtin_bit_cast(half2_, h), acc, false);
#else
    half2_ a = __builtin_bit_cast(half2_, w);
    half2_ b = __builtin_bit_cast(half2_, h);
    return acc + (float)a.x * (float)b.x + (float)a.y * (float)b.y;
#endif
}

// ---------------------------------------------------------------------------
// Segment-reduce stage 1: partial bin sums over a 128-timestep slice.
// Grid (64 b, 3 chunks, 4 tsplit), block 256. Thread owns one feature column
// -> race-free LDS accumulation (no atomics). part[b][chunk][ts][50][256].
// ---------------------------------------------------------------------------
__global__ __launch_bounds__(256) void seg_part(
    const float* __restrict__ hidden, const int* __restrict__ mask,
    float* __restrict__ part) {
    int b = blockIdx.x, chunk = blockIdx.y, ts = blockIdx.z;
    __shared__ float acc[50 * 256];
    __shared__ int mloc[128];
    int tid = threadIdx.x;
    for (int i = tid; i < 50 * 256; i += 256) acc[i] = 0.f;
    if (tid < 128) mloc[tid] = mask[b * 512 + ts * 128 + tid];
    __syncthreads();
    const float* hb = hidden + ((size_t)b * 512 + ts * 128) * 768 + chunk * 256 + tid;
    #pragma unroll 4
    for (int t = 0; t < 128; t++) {
        float v = hb[(size_t)t * 768];
        int d = mloc[t];
        if (d >= 0 && d < 50) acc[d * 256 + tid] += v;
    }
    __syncthreads();
    float* dst = part + (((size_t)(b * 3 + chunk) * 4 + ts) * 12800);
    for (int i = tid; i < 12800; i += 256) dst[i] = acc[i];
}

// ---------------------------------------------------------------------------
// Segment-reduce stage 2: sum 4 partials, /50, concat lstm_input, pad, bf16.
// Flat grid over 64*50*832 outputs.
// ---------------------------------------------------------------------------
__global__ __launch_bounds__(256) void seg_final(
    const float* __restrict__ part, const float* __restrict__ lstm_in,
    short* __restrict__ concatB) {
    int idx = blockIdx.x * 256 + threadIdx.x;  // = (b*50+m)*832 + j
    int j = idx % 832;
    int bm = idx / 832;
    int m = bm % 50, b = bm / 50;
    float v;
    if (j < 768) {
        int chunk = j >> 8, jj = j & 255;
        const float* p = part + ((size_t)(b * 3 + chunk) * 4) * 12800 + m * 256 + jj;
        float s = (p[0] + p[12800]) + (p[2 * 12800] + p[3 * 12800]);
        v = s * (1.f / 50.f);
    } else if (j < 776) {
        v = lstm_in[(b * 50 + m) * 8 + (j - 768)];
    } else {
        v = 0.f;
    }
    concatB[idx] = (short)f2bf(v);
}

// ---------------------------------------------------------------------------
// Kernel W: transpose+convert kernel weights: src[K][Nhalf] f32 (two halves)
// -> dst[N=2*Nhalf][Kpad] bf16 for the MFMA GEMM (B^T layout).
// ---------------------------------------------------------------------------
__global__ __launch_bounds__(256) void convT(
    const float* __restrict__ srcF, const float* __restrict__ srcB,
    short* __restrict__ dst, int Ksrc, int Kpad, int Nhalf) {
    int k0 = blockIdx.x * 64, n0 = blockIdx.y * 64;
    const float* src = (n0 < Nhalf) ? srcF : srcB;
    int ncol0 = (n0 < Nhalf) ? n0 : n0 - Nhalf;
    __shared__ float tile[64][65];
    int c = threadIdx.x & 63;
    int r4 = threadIdx.x >> 6;
    for (int rr = r4; rr < 64; rr += 4) {
        int k = k0 + rr;
        tile[rr][c] = (k < Ksrc) ? src[(size_t)k * Nhalf + ncol0 + c] : 0.f;
    }
    __syncthreads();
    int rn = threadIdx.x >> 2, q = threadIdx.x & 3;
    short* d = dst + (size_t)(n0 + rn) * Kpad + k0 + q * 16;
    #pragma unroll
    for (int i = 0; i < 16; i++) d[i] = (short)f2bf(tile[q * 16 + i][rn]);
}

// ---------------------------------------------------------------------------
// Kernel Wr: recurrence weights f32 [K][N] (per dir) -> u32 [2][K/8][N][4]
// packed f16 pairs.
// ---------------------------------------------------------------------------
__global__ __launch_bounds__(256) void conv_rec_pack(
    const float* __restrict__ WrF, const float* __restrict__ WrB,
    unsigned int* __restrict__ dst, int K, int N) {
    int kq = blockIdx.x, dir = blockIdx.y;
    const float* src = dir ? WrB : WrF;
    int kqq = kq >> 2, q = kq & 3;
    for (int c = threadIdx.x; c < N; c += 256) {
        half2_ h;
        h.x = (_Float16)src[(size_t)(2 * kq) * N + c];
        h.y = (_Float16)src[(size_t)(2 * kq + 1) * N + c];
        dst[(((size_t)dir * (K / 8) + kqq) * N + c) * 4 + q] =
            __builtin_bit_cast(unsigned int, h);
    }
}

// ---------------------------------------------------------------------------
// bf16 MFMA GEMM: C[M][N] = A[M][Kpad] * BT[N][Kpad]^T + bias.
// ---------------------------------------------------------------------------
__global__ __launch_bounds__(256) void gemm_bf16(
    const short* __restrict__ A, const short* __restrict__ BT,
    const float* __restrict__ biasF, const float* __restrict__ biasB, int Nhalf,
    float* __restrict__ C, int M, int N, int Kpad) {
    __shared__ short Al[128][48];
    __shared__ short Bl[128][48];
    int m0 = blockIdx.x * 128, n0 = blockIdx.y * 128;
    int tid = threadIdx.x;
    int lane = tid & 63, w = tid >> 6;
    int arow = tid >> 1, ahalf = tid & 1;
    int wr = (w >> 1) * 64, wc = (w & 1) * 64;
    int fr = lane & 15, fq = lane >> 4;

    f32x4 acc[4][4] = {};

    for (int k0 = 0; k0 < Kpad; k0 += 32) {
        bf16x8 av = *(const bf16x8*)(A + (size_t)(m0 + arow) * Kpad + k0 + ahalf * 16);
        bf16x8 bv = *(const bf16x8*)(BT + (size_t)(n0 + arow) * Kpad + k0 + ahalf * 16);
        *(bf16x8*)&Al[arow][ahalf * 16] = av;
        *(bf16x8*)&Bl[arow][ahalf * 16] = bv;
        __syncthreads();
        bf16x8 af[4], bfv[4];
        #pragma unroll
        for (int mi = 0; mi < 4; mi++)
            af[mi] = *(const bf16x8*)&Al[wr + mi * 16 + fr][fq * 8];
        #pragma unroll
        for (int ni = 0; ni < 4; ni++)
            bfv[ni] = *(const bf16x8*)&Bl[wc + ni * 16 + fr][fq * 8];
        #pragma unroll
        for (int mi = 0; mi < 4; mi++)
            #pragma unroll
            for (int ni = 0; ni < 4; ni++)
                acc[mi][ni] = __builtin_amdgcn_mfma_f32_16x16x32_bf16(
                    af[mi], bfv[ni], acc[mi][ni], 0, 0, 0);
        __syncthreads();
    }
    #pragma unroll
    for (int mi = 0; mi < 4; mi++)
        #pragma unroll
        for (int ni = 0; ni < 4; ni++) {
            #pragma unroll
            for (int r = 0; r < 4; r++) {
                int row = m0 + wr + mi * 16 + fq * 4 + r;
                int col = n0 + wc + ni * 16 + fr;
                float bias = (col < Nhalf) ? biasF[col] : biasB[col - Nhalf];
                C[(size_t)row * N + col] = acc[mi][ni][r] + bias;
            }
        }
}

// ---------------------------------------------------------------------------
// LSTM layer-1 recurrence. One block per (batch, dir); 512 threads.
// Weights f16-pair-packed: k<192 in registers, k in [192,256) in LDS.
// ---------------------------------------------------------------------------
#define KQQ_REG 24
#define KQQ_LDS 8

__global__ __launch_bounds__(512, 2) void lstm_rec1(
    const float* __restrict__ xz, const unsigned int* __restrict__ wp,
    short* __restrict__ out1) {
    int b = blockIdx.x >> 1, dir = blockIdx.x & 1;
    const unsigned int* wd = wp + (size_t)dir * 32 * 1024 * 4;
    extern __shared__ char smem[];
    unsigned int* Wl = (unsigned int*)smem;               // 8*1024*4 u32 = 128 KB
    unsigned int* h2u = (unsigned int*)(smem + 131072);   // 128 u32 (256 f16)
    float* zbuf = (float*)(smem + 131072 + 512);          // 1024 f32
    int t = threadIdx.x;
    int cA = t, cB = t + 512;

    u32x4 wA[KQQ_REG], wB[KQQ_REG];
    #pragma unroll
    for (int g = 0; g < KQQ_REG; g++) {
        wA[g] = *(const u32x4*)&wd[((size_t)g * 1024 + cA) * 4];
        wB[g] = *(const u32x4*)&wd[((size_t)g * 1024 + cB) * 4];
    }
    #pragma unroll
    for (int g = 0; g < KQQ_LDS; g++) {
        *(u32x4*)&Wl[(g * 1024 + cA) * 4] =
            *(const u32x4*)&wd[((size_t)(KQQ_REG + g) * 1024 + cA) * 4];
        *(u32x4*)&Wl[(g * 1024 + cB) * 4] =
            *(const u32x4*)&wd[((size_t)(KQQ_REG + g) * 1024 + cB) * 4];
    }
    if (t < 128) h2u[t] = 0u;
    float cstate = 0.f;
    __syncthreads();

    for (int s = 0; s < 50; s++) {
        int tt = dir ? 49 - s : s;
        const float* xrow = xz + (size_t)(b * 50 + tt) * 2048 + dir * 1024;
        float zA0 = xrow[cA], zA1 = 0.f;
        float zB0 = xrow[cB], zB1 = 0.f;
        #pragma unroll
        for (int g = 0; g < KQQ_REG; g++) {
            u32x4 h4 = *(const u32x4*)&h2u[g * 4];
            zA0 = fdot2_(wA[g].x, h4.x, zA0);
            zA1 = fdot2_(wA[g].y, h4.y, zA1);
            zA0 = fdot2_(wA[g].z, h4.z, zA0);
            zA1 = fdot2_(wA[g].w, h4.w, zA1);
            zB0 = fdot2_(wB[g].x, h4.x, zB0);
            zB1 = fdot2_(wB[g].y, h4.y, zB1);
            zB0 = fdot2_(wB[g].z, h4.z, zB0);
            zB1 = fdot2_(wB[g].w, h4.w, zB1);
        }
        #pragma unroll
        for (int g = 0; g < KQQ_LDS; g++) {
            u32x4 h4 = *(const u32x4*)&h2u[(KQQ_REG + g) * 4];
            u32x4 wa = *(const u32x4*)&Wl[(g * 1024 + cA) * 4];
            u32x4 wb = *(const u32x4*)&Wl[(g * 1024 + cB) * 4];
            zA0 = fdot2_(wa.x, h4.x, zA0);
            zA1 = fdot2_(wa.y, h4.y, zA1);
            zA0 = fdot2_(wa.z, h4.z, zA0);
            zA1 = fdot2_(wa.w, h4.w, zA1);
            zB0 = fdot2_(wb.x, h4.x, zB0);
            zB1 = fdot2_(wb.y, h4.y, zB1);
            zB0 = fdot2_(wb.z, h4.z, zB0);
            zB1 = fdot2_(wb.w, h4.w, zB1);
        }
        zbuf[cA] = zA0 + zA1;
        zbuf[cB] = zB0 + zB1;
        __syncthreads();
        if (t < 256) {
            float iv = sigmoidf_(zbuf[t]);
            float fv = sigmoidf_(zbuf[t + 256]);
            float gv = tanhf_(zbuf[t + 512]);
            float ov = sigmoidf_(zbuf[t + 768]);
            cstate = fv * cstate + iv * gv;
            float h = ov * tanhf_(cstate);
            ((_Float16*)h2u)[t] = (_Float16)h;
            out1[(size_t)(b * 50 + tt) * 512 + dir * 256 + t] = (short)f2bf(h);
        }
        __syncthreads();
    }
}

// ---------------------------------------------------------------------------
// LSTM layer-2 recurrence. One block per (batch, dir); 512 threads.
// ALL K=128 weights in registers (16 u32x4).
// ---------------------------------------------------------------------------
__global__ __launch_bounds__(512, 2) void lstm_rec2(
    const float* __restrict__ xz, const unsigned int* __restrict__ wp,
    float* __restrict__ out2) {
    int b = blockIdx.x >> 1, dir = blockIdx.x & 1;
    const unsigned int* wd = wp + (size_t)dir * 16 * 512 * 4;
    __shared__ unsigned int h2u[64];
    __shared__ float zbuf[512];
    int t = threadIdx.x;
    u32x4 w[16];
    #pragma unroll
    for (int g = 0; g < 16; g++)
        w[g] = *(const u32x4*)&wd[((size_t)g * 512 + t) * 4];
    if (t < 64) h2u[t] = 0u;
    float cstate = 0.f;
    __syncthreads();

    for (int s = 0; s < 50; s++) {
        int tt = dir ? 49 - s : s;
        float z0 = xz[(size_t)(b * 50 + tt) * 1024 + dir * 512 + t], z1 = 0.f;
        #pragma unroll
        for (int g = 0; g < 16; g++) {
            u32x4 h4 = *(const u32x4*)&h2u[g * 4];
            z0 = fdot2_(w[g].x, h4.x, z0);
            z1 = fdot2_(w[g].y, h4.y, z1);
            z0 = fdot2_(w[g].z, h4.z, z0);
            z1 = fdot2_(w[g].w, h4.w, z1);
        }
        zbuf[t] = z0 + z1;
        __syncthreads();
        if (t < 128) {
            float iv = sigmoidf_(zbuf[t]);
            float fv = sigmoidf_(zbuf[t + 128]);
            float gv = tanhf_(zbuf[t + 256]);
            float ov = sigmoidf_(zbuf[t + 384]);
            cstate = fv * cstate + iv * gv;
            float h = ov * tanhf_(cstate);
            ((_Float16*)h2u)[t] = (_Float16)h;
            if (s == 49) out2[b * 256 + dir * 128 + t] = h;
        }
        __syncthreads();
    }
}

// ---------------------------------------------------------------------------
// Dense head: 256->128->64->32->1 with relu/sigmoid. One block per batch.
// ---------------------------------------------------------------------------
__global__ __launch_bounds__(128) void dense_head(
    const float* __restrict__ out2,
    const float* __restrict__ d1w, const float* __restrict__ d1b,
    const float* __restrict__ d3w, const float* __restrict__ d3b,
    const float* __restrict__ d5w, const float* __restrict__ d5b,
    const float* __restrict__ d7w, const float* __restrict__ d7b,
    float* __restrict__ out) {
    int b = blockIdx.x;
    int tid = threadIdx.x;
    __shared__ float x[256], y1[128], y2[64], y3[32];
    x[tid] = out2[b * 256 + tid];
    x[tid + 128] = out2[b * 256 + tid + 128];
    __syncthreads();
    {
        float a = d1b[tid];
        for (int k = 0; k < 256; k++) a = fmaf(x[k], d1w[k * 128 + tid], a);
        y1[tid] = fmaxf(a, 0.f);
    }
    __syncthreads();
    if (tid < 64) {
        float a = d3b[tid];
        for (int k = 0; k < 128; k++) a = fmaf(y1[k], d3w[k * 64 + tid], a);
        y2[tid] = fmaxf(a, 0.f);
    }
    __syncthreads();
    if (tid < 32) {
        float a = d5b[tid];
        for (int k = 0; k < 64; k++) a = fmaf(y2[k], d5w[k * 32 + tid], a);
        y3[tid] = fmaxf(a, 0.f);
    }
    __syncthreads();
    if (tid == 0) {
        float a = d7b[0];
        for (int k = 0; k < 32; k++) a = fmaf(y3[k], d7w[k], a);
        out[b] = 1.f / (1.f + __expf(-a));
    }
}

extern "C" void kernel_launch(void* const* d_in, const int* in_sizes, int n_in,
                              void* d_out, int out_size, void* d_ws, size_t ws_size,
                              hipStream_t stream) {
    const float* hidden  = (const float*)d_in[0];
    const int*   mask    = (const int*)d_in[1];
    const float* lstm_in = (const float*)d_in[2];
    const float* l1f_k = (const float*)d_in[4];
    const float* l1f_r = (const float*)d_in[5];
    const float* l1f_b = (const float*)d_in[6];
    const float* l1b_k = (const float*)d_in[7];
    const float* l1b_r = (const float*)d_in[8];
    const float* l1b_b = (const float*)d_in[9];
    const float* l2f_k = (const float*)d_in[10];
    const float* l2f_r = (const float*)d_in[11];
    const float* l2f_b = (const float*)d_in[12];
    const float* l2b_k = (const float*)d_in[13];
    const float* l2b_r = (const float*)d_in[14];
    const float* l2b_b = (const float*)d_in[15];
    const float* d1w = (const float*)d_in[16];
    const float* d1b = (const float*)d_in[17];
    const float* d3w = (const float*)d_in[18];
    const float* d3b = (const float*)d_in[19];
    const float* d5w = (const float*)d_in[20];
    const float* d5b = (const float*)d_in[21];
    const float* d7w = (const float*)d_in[22];
    const float* d7b = (const float*)d_in[23];

    char* p = (char*)d_ws;
    short* concatB = (short*)p; p += (size_t)3200 * 832 * 2;
    short* wk1T    = (short*)p; p += (size_t)2048 * 832 * 2;
    short* wk2T    = (short*)p; p += (size_t)1024 * 512 * 2;
    float* xz1     = (float*)p; p += (size_t)3200 * 2048 * 4;
    short* out1    = (short*)p; p += (size_t)3200 * 512 * 2;
    float* xz2     = (float*)p; p += (size_t)3200 * 1024 * 4;
    float* out2    = (float*)p; p += (size_t)64 * 256 * 4;
    unsigned int* wp1 = (unsigned int*)p; p += (size_t)2 * 32 * 1024 * 4 * 4;
    unsigned int* wp2 = (unsigned int*)p; p += (size_t)2 * 16 * 512 * 4 * 4;

    // part[64][3][4][50][256] f32 = 39.3 MB, aliased onto xz1/out1/xz2
    // (dead until gemm1, which runs after seg_final on the serial stream).
    float* part = xz1;

    const int lds1 = 131072 + 512 + 4096;  // 135680
    hipFuncSetAttribute((const void*)lstm_rec1,
                        hipFuncAttributeMaxDynamicSharedMemorySize, lds1);

    seg_part<<<dim3(64, 3, 4), 256, 0, stream>>>(hidden, mask, part);
    seg_final<<<(64 * 50 * 832) / 256, 256, 0, stream>>>(part, lstm_in, concatB);
    convT<<<dim3(13, 32), 256, 0, stream>>>(l1f_k, l1b_k, wk1T, 776, 832, 1024);
    convT<<<dim3(8, 16), 256, 0, stream>>>(l2f_k, l2b_k, wk2T, 512, 512, 512);
    conv_rec_pack<<<dim3(128, 2), 256, 0, stream>>>(l1f_r, l1b_r, wp1, 256, 1024);
    conv_rec_pack<<<dim3(64, 2), 256, 0, stream>>>(l2f_r, l2b_r, wp2, 128, 512);
    gemm_bf16<<<dim3(25, 16), 256, 0, stream>>>(concatB, wk1T, l1f_b, l1b_b, 1024,
                                                xz1, 3200, 2048, 832);
    lstm_rec1<<<128, 512, lds1, stream>>>(xz1, wp1, out1);
    gemm_bf16<<<dim3(25, 8), 256, 0, stream>>>(out1, wk2T, l2f_b, l2b_b, 512,
                                               xz2, 3200, 1024, 512);
    lstm_rec2<<<128, 512, 0, stream>>>(xz2, wp2, out2);
    dense_head<<<64, 128, 0, stream>>>(out2, d1w, d1b, d3w, d3b, d5w, d5b,
                                       d7w, d7b, (float*)d_out);
}